// Round 13
// baseline (518.924 us; speedup 1.0000x reference)
//
#include <hip/hip_runtime.h>
#include <cstdint>
#include <cstddef>

#define T_LEN 2048
#define PAST_MAX 2048
#define HID 4096
#define NHEAD 32
#define DHEAD 128

typedef __bf16 bf16_t;
typedef __bf16 bf16x4 __attribute__((ext_vector_type(4)));
typedef __bf16 bf16x8 __attribute__((ext_vector_type(8)));
typedef float  f32x4  __attribute__((ext_vector_type(4)));
typedef float  f32x16 __attribute__((ext_vector_type(16)));
typedef unsigned int u32x4 __attribute__((ext_vector_type(4)));
typedef unsigned int u32x2 __attribute__((ext_vector_type(2)));

__device__ __forceinline__ void gload16(const void* g, void* l){
  __builtin_amdgcn_global_load_lds((const __attribute__((address_space(1))) void*)g,
                                   (__attribute__((address_space(3))) void*)l,
                                   16, 0, 0);
}

__device__ __forceinline__ unsigned pack_bf16(float a, float b){
  const unsigned ua = __builtin_bit_cast(unsigned short, (bf16_t)a);
  const unsigned ub = __builtin_bit_cast(unsigned short, (bf16_t)b);
  return ua | (ub << 16);
}

// raw v_exp_f32 (exp2) — avoid OCML exp2f's edge-handling overhead (R10 lesson:
// VALUBusy 37->47% from library exp2f; __builtin/asm emits the bare instruction).
#if __has_builtin(__builtin_amdgcn_exp2f)
__device__ __forceinline__ float exp2_raw(float x){ return __builtin_amdgcn_exp2f(x); }
#else
__device__ __forceinline__ float exp2_raw(float x){
  float r; asm("v_exp_f32 %0, %1" : "=v"(r) : "v"(x)); return r;
}
#endif

// ---------------- fused f32 -> bf16 for X and past_k ----------------
__global__ void cvt2_k(const float* __restrict__ a, bf16_t* __restrict__ ao,
                       const float* __restrict__ b, bf16_t* __restrict__ bo, int n4){
  int i = blockIdx.x * 256 + threadIdx.x;
  if (i < n4){
    const float4 v = ((const float4*)a)[i];
    bf16x4 o = { (bf16_t)v.x, (bf16_t)v.y, (bf16_t)v.z, (bf16_t)v.w };
    ((bf16x4*)ao)[i] = o;
  } else {
    i -= n4;
    const float4 v = ((const float4*)b)[i];
    bf16x4 o = { (bf16_t)v.x, (bf16_t)v.y, (bf16_t)v.z, (bf16_t)v.w };
    ((bf16x4*)bo)[i] = o;
  }
}

// ---------------- f32 [B][R][C] -> bf16 [B][C][R], 64x64 tiles ----------------
__global__ __launch_bounds__(256) void transpose2_k(const float* __restrict__ in,
                                                    bf16_t* __restrict__ out, int R, int C){
  __shared__ float tile[64][65];
  const int r0 = blockIdx.x << 6, c0 = blockIdx.y << 6;
  const size_t bo = (size_t)blockIdx.z * (size_t)R * (size_t)C;
  const int tx = threadIdx.x & 15, ty = threadIdx.x >> 4;
#pragma unroll
  for (int k = 0; k < 4; ++k){
    const float4 v = *(const float4*)(in + bo + (size_t)(r0 + ty + 16*k) * C + c0 + tx*4);
    float* tp = &tile[ty + 16*k][tx*4];
    tp[0] = v.x; tp[1] = v.y; tp[2] = v.z; tp[3] = v.w;
  }
  __syncthreads();
  const int rr0 = (threadIdx.x & 7) * 8;
  const int ccb = threadIdx.x >> 3;     // 0..31
#pragma unroll
  for (int k = 0; k < 2; ++k){
    const int cc = ccb + 32*k;
    bf16x8 o;
#pragma unroll
    for (int j = 0; j < 8; ++j) o[j] = (bf16_t)tile[rr0 + j][cc];
    *(bf16x8*)(out + bo + (size_t)(c0 + cc) * R + r0 + rr0) = o;
  }
}

// ---------------- fused transpose of Wq/Wk/Wv (z selects) ----------------
__global__ __launch_bounds__(256) void transpose3_k(
    const float* __restrict__ s0, const float* __restrict__ s1, const float* __restrict__ s2,
    bf16_t* __restrict__ d0, bf16_t* __restrict__ d1, bf16_t* __restrict__ d2){
  __shared__ float tile[64][65];
  const float* in = (blockIdx.z == 0) ? s0 : (blockIdx.z == 1) ? s1 : s2;
  bf16_t* out = (blockIdx.z == 0) ? d0 : (blockIdx.z == 1) ? d1 : d2;
  const int r0 = blockIdx.x << 6, c0 = blockIdx.y << 6;
  const int tx = threadIdx.x & 15, ty = threadIdx.x >> 4;
#pragma unroll
  for (int k = 0; k < 4; ++k){
    const float4 v = *(const float4*)(in + (size_t)(r0 + ty + 16*k) * HID + c0 + tx*4);
    float* tp = &tile[ty + 16*k][tx*4];
    tp[0] = v.x; tp[1] = v.y; tp[2] = v.z; tp[3] = v.w;
  }
  __syncthreads();
  const int rr0 = (threadIdx.x & 7) * 8;
  const int ccb = threadIdx.x >> 3;
#pragma unroll
  for (int k = 0; k < 2; ++k){
    const int cc = ccb + 32*k;
    bf16x8 o;
#pragma unroll
    for (int j = 0; j < 8; ++j) o[j] = (bf16_t)tile[rr0 + j][cc];
    *(bf16x8*)(out + (size_t)(c0 + cc) * HID + r0 + rr0) = o;
  }
}

// -------- RoPE in place on K only, bf16x8-vectorized (Q roped in-register in attn) -----
__global__ void ropek8_k(bf16_t* __restrict__ K, const int* __restrict__ pos){
  const int idx = blockIdx.x * 256 + threadIdx.x;     // 2048*256 = 512K threads
  const int jc = idx & 7;                             // 8-elem chunk within d<64
  const int t  = (idx >> 3) & (T_LEN - 1);
  const int h  = idx >> 14;
  const size_t base = ((size_t)h * T_LEN + t) * DHEAD;
  const float p = (float)pos[t];
  bf16x8 lo = *(bf16x8*)(K + base + jc * 8);
  bf16x8 hi = *(bf16x8*)(K + base + 64 + jc * 8);
  bf16x8 olo, ohi;
#pragma unroll
  for (int j = 0; j < 8; ++j){
    const int fi = jc * 8 + j;
    const float invf = __expf(-(float)fi * 0.14391156605212898f);  // ln(10000)/64
    float sn, cs;
    sincosf(p * invf, &sn, &cs);
    const float b0 = (float)lo[j], b1 = (float)hi[j];
    olo[j] = (bf16_t)(b0 * cs - b1 * sn);
    ohi[j] = (bf16_t)(b1 * cs + b0 * sn);
  }
  *(bf16x8*)(K + base + jc * 8) = olo;
  *(bf16x8*)(K + base + 64 + jc * 8) = ohi;
}

// ===================== shared schedule macros (R8-proven) ==============================
#define MM6(AF, BF, PR) \
  __builtin_amdgcn_s_setprio(1); \
  _Pragma("unroll") \
  for (int kk = 0; kk < 2; ++kk){ \
    _Pragma("unroll") \
    for (int mf = 0; mf < 4; ++mf){ \
      _Pragma("unroll") \
      for (int ni = 0; ni < 2; ++ni) \
        acc[mf][(PR)*2 + ni] = __builtin_amdgcn_mfma_f32_16x16x32_bf16( \
            AF[mf][kk], BF[ni][kk], acc[mf][(PR)*2 + ni], 0, 0, 0); \
    } \
  } \
  __builtin_amdgcn_s_setprio(0); \
  __builtin_amdgcn_sched_barrier(0);

#define RDA(SET, BUF) \
  _Pragma("unroll") \
  for (int mf = 0; mf < 4; ++mf){ \
    SET[mf][0] = *(const bf16x8*)((BUF) + abase + mf * 2048 + koff0); \
    SET[mf][1] = *(const bf16x8*)((BUF) + abase + mf * 2048 + koff1); \
  }

#define RDB(SET, BUF, UOFF) \
  _Pragma("unroll") \
  for (int ni = 0; ni < 2; ++ni){ \
    SET[ni][0] = *(const bf16x8*)((BUF) + (UOFF) + bbase + ni * 2048 + koff0); \
    SET[ni][1] = *(const bf16x8*)((BUF) + (UOFF) + bbase + ni * 2048 + koff1); \
  }

#define PTOPX(N) \
  asm volatile("s_waitcnt vmcnt(" #N ")" ::: "memory"); \
  __builtin_amdgcn_s_barrier(); \
  __builtin_amdgcn_sched_barrier(0);

#define LGK(N) \
  __builtin_amdgcn_sched_barrier(0); \
  asm volatile("s_waitcnt lgkmcnt(" #N ")" ::: "memory"); \
  __builtin_amdgcn_sched_barrier(0);

// ========= QKV: 128x384 BK=64, cross-phase read-ahead + counted lgkm (R8-proven) =======
// 189 us, MfmaUtil 49%. Unchanged from R8.
__global__ __launch_bounds__(512, 1) void gemmqkv6p_k(
    const bf16_t* __restrict__ A,
    const bf16_t* __restrict__ Bc,       // concatenated W^T: [12288][4096]
    bf16_t* __restrict__ OQ, bf16_t* __restrict__ OK2, bf16_t* __restrict__ OVT)
{
  const int bid = blockIdx.x;
  const int wg  = (bid & 7) * 64 + (bid >> 3);   // 512 % 8 == 0 -> bijective XCD chunking
  const int mt  = wg & 15;                        // 16 M-tiles of 128
  const int nt  = wg >> 4;                        // 32 N-tiles of 384
  const int m0  = mt << 7;
  const int n0g = nt * 384;

  const int tid = threadIdx.x;
  const int wv = tid >> 6, lane = tid & 63, lm = lane & 15, g = lane >> 4;
  const int wr = wv >> 2, wc = wv & 3;   // 2 M-groups x 4 N-groups (wave tile 64x96)

  __shared__ __align__(16) char smem[131072];  // [buf][ A 16K | B0 16K | B1 16K | B2 16K ]
  char* const buf0 = smem;            // even K-tiles
  char* const buf1 = smem + 65536;    // odd K-tiles

  const f32x4 fzero = {0.f, 0.f, 0.f, 0.f};
  f32x4 acc[4][6];
#pragma unroll
  for (int i = 0; i < 4; ++i)
#pragma unroll
    for (int j = 0; j < 6; ++j) acc[i][j] = fzero;

  // staging decode: unit = 1024 chunks of 16B, 8 chunks per 128B row; source pre-swizzled
  size_t aoff[2], boff[2];
#pragma unroll
  for (int i = 0; i < 2; ++i){
    const int c = i * 512 + tid;
    const int u = c >> 3;                       // row-within-unit 0..127
    const int j = ((c & 7) ^ (u & 7)) << 3;     // element offset of 16B chunk
    aoff[i] = (size_t)(m0 + u) * HID + j;
    const int bcol = (u >> 5) * 96 + (u & 31);  // + pr*32 at call
    boff[i] = (size_t)(n0g + bcol) * HID + j;
  }
  const int ldst0 = (wv * 64) << 4;
  const int ldst1 = (512 + wv * 64) << 4;

  auto stgA = [&](char* buf, int kt){
    if ((unsigned)kt < 64u){
      const bf16_t* src = A + (size_t)kt * 64;
      gload16(src + aoff[0], buf + ldst0);
      gload16(src + aoff[1], buf + ldst1);
    }
  };
  auto stgB = [&](char* buf, int kt, int pr){
    if ((unsigned)kt < 64u){
      const bf16_t* src = Bc + (size_t)kt * 64 + (size_t)pr * (32 * HID);
      char* dst = buf + 16384 + pr * 16384;
      gload16(src + boff[0], dst + ldst0);
      gload16(src + boff[1], dst + ldst1);
    }
  };

  // fragment read constants (frag rows == lm mod 8 -> lane-constant swizzle)
  const int koff0 = ((0 + g) ^ (lm & 7)) << 4;
  const int koff1 = ((4 + g) ^ (lm & 7)) << 4;
  const int abase = ((wr << 6) + lm) << 7;      // + mf*2048
  const int bbase = ((wc << 5) + lm) << 7;      // + ni*2048 (within unit)

  // prologue: kt0 fully (loads 1-8), kt1 {A,B0,B1} (loads 9-14); vmcnt(6) -> kt0 done.
  stgA(buf0, 0); stgB(buf0, 0, 0); stgB(buf0, 0, 1); stgB(buf0, 0, 2);
  stgA(buf1, 1); stgB(buf1, 1, 0); stgB(buf1, 1, 1);
  asm volatile("s_waitcnt vmcnt(6)" ::: "memory");
  __builtin_amdgcn_s_barrier();

  bf16x8 afA[4][2], afB[4][2], bU[2][2], bV[2][2];
  RDA(afA, buf0)                 // A(0)
  RDB(bU, buf0, 16384)           // B0(0)

  for (int i = 0; i < 31; ++i){
    const int kt0 = 2 * i;
    // ---- P1 = ph1(kt0): MFMA A x B0; read B1(kt0); stage B2(kt0+1) ----
    PTOPX(8)
    RDB(bV, buf0, 32768)
    stgB(buf1, kt0 + 1, 2);
    LGK(4)
    MM6(afA, bU, 0)
    // ---- P2 = ph2(kt0): MFMA A x B1; read B2(kt0); stage A,B0(kt0+2) ----
    PTOPX(8)
    RDB(bU, buf0, 49152)
    stgA(buf0, kt0 + 2); stgB(buf0, kt0 + 2, 0);
    LGK(4)
    MM6(afA, bV, 1)
    // ---- P3 = ph3(kt0): MFMA A x B2; read A,B0(kt0+1); stage B1(kt0+2) ----
    PTOPX(8)
    RDA(afB, buf1)
    RDB(bV, buf1, 16384)
    stgB(buf0, kt0 + 2, 1);
    LGK(12)
    MM6(afA, bU, 2)
    // ---- P4 = ph1(kt0+1): MFMA A' x B0'; read B1(kt0+1); stage B2(kt0+2) ----
    PTOPX(8)
    RDB(bU, buf1, 32768)
    stgB(buf0, kt0 + 2, 2);
    LGK(4)
    MM6(afB, bV, 0)
    // ---- P5 = ph2(kt0+1): MFMA A' x B1'; read B2(kt0+1); stage A,B0(kt0+3) ----
    PTOPX(8)
    RDB(bV, buf1, 49152)
    stgA(buf1, kt0 + 3); stgB(buf1, kt0 + 3, 0);
    LGK(4)
    MM6(afB, bU, 1)
    // ---- P6 = ph3(kt0+1): MFMA A' x B2'; read A,B0(kt0+2); stage B1(kt0+3) ----
    PTOPX(8)
    RDA(afA, buf0)
    RDB(bU, buf0, 16384)
    stgB(buf1, kt0 + 3, 1);
    LGK(12)
    MM6(afB, bV, 2)
  }

  // ---- peeled final iteration: kt = 62, 63 (fully drained phase tops, no stages) ----
  PTOPX(0)
  RDB(bV, buf0, 32768)           // B1(62)
  stgB(buf1, 63, 2);             // B2(63)
  LGK(4)
  MM6(afA, bU, 0)
  PTOPX(0)
  RDB(bU, buf0, 49152)           // B2(62)
  LGK(4)
  MM6(afA, bV, 1)
  PTOPX(0)
  RDA(afB, buf1)                 // A(63)
  RDB(bV, buf1, 16384)           // B0(63)
  LGK(12)
  MM6(afA, bU, 2)
  PTOPX(0)
  RDB(bU, buf1, 32768)           // B1(63)
  LGK(4)
  MM6(afB, bV, 0)
  PTOPX(0)
  RDB(bV, buf1, 49152)           // B2(63)
  LGK(4)
  MM6(afB, bU, 1)
  LGK(0)
  MM6(afB, bV, 2)

  // epilogue: per-16-col-block z select (blocks never straddle 4096 boundaries)
#pragma unroll
  for (int pr = 0; pr < 3; ++pr)
#pragma unroll
    for (int ni = 0; ni < 2; ++ni){
      const int colg = n0g + wc * 96 + pr * 32 + ni * 16 + lm;
      const int z  = colg >> 12;
      const int wi = colg & 4095;
      const int hh = wi >> 7, dd = wi & 127;
      const int ai = pr * 2 + ni;
#pragma unroll
      for (int mf = 0; mf < 4; ++mf){
        const int trow0 = m0 + wr * 64 + mf * 16 + g * 4;
        if (z == 2){
          bf16x4 v4 = { (bf16_t)acc[mf][ai][0], (bf16_t)acc[mf][ai][1],
                        (bf16_t)acc[mf][ai][2], (bf16_t)acc[mf][ai][3] };
          *(bf16x4*)(OVT + ((size_t)hh * DHEAD + dd) * T_LEN + trow0) = v4;
        } else {
          bf16_t* ob = z ? OK2 : OQ;
#pragma unroll
          for (int r = 0; r < 4; ++r)
            ob[((size_t)hh * T_LEN + trow0 + r) * DHEAD + dd] = (bf16_t)acc[mf][ai][r];
        }
      }
    }
}

// ====== out-proj: 128x256 BK=64, cross-phase read-ahead port (R8 schedule, 2-phase) ====
__global__ __launch_bounds__(512, 1) void gemmop_ra_k(
    const bf16_t* __restrict__ A, const bf16_t* __restrict__ B,
    float* __restrict__ OF)
{
  const int bid = blockIdx.x;
  const int wg  = (bid & 7) * 32 + (bid >> 3);   // 256 % 8 == 0 -> bijective
  const int mt  = wg & 15;                        // 16 M-tiles of 128
  const int nt  = wg >> 4;                        // 16 N-tiles of 256
  const int m0  = mt << 7;
  const int n0  = nt << 8;

  const int tid = threadIdx.x;
  const int wv = tid >> 6, lane = tid & 63, lm = lane & 15, g = lane >> 4;
  const int wr = wv >> 2, wc = wv & 3;   // 2 M-groups x 4 N-groups (wave tile 64x64)

  __shared__ __align__(16) char smem[98304];   // [buf][ A 16K | B0 16K | B1 16K ]
  char* const buf0 = smem;
  char* const buf1 = smem + 49152;

  const f32x4 fzero = {0.f, 0.f, 0.f, 0.f};
  f32x4 acc[4][4];
#pragma unroll
  for (int i = 0; i < 4; ++i)
#pragma unroll
    for (int j = 0; j < 4; ++j) acc[i][j] = fzero;

  size_t aoff[2], boff[2];
#pragma unroll
  for (int i = 0; i < 2; ++i){
    const int c = i * 512 + tid;
    const int u = c >> 3;
    const int j = ((c & 7) ^ (u & 7)) << 3;
    aoff[i] = (size_t)(m0 + u) * HID + j;
    const int bcol = (u >> 5) * 64 + (u & 31);  // + pr*32 at call
    boff[i] = (size_t)(n0 + bcol) * HID + j;
  }
  const int ldst0 = (wv * 64) << 4;
  const int ldst1 = (512 + wv * 64) << 4;

  auto stgA = [&](char* buf, int kt){
    if ((unsigned)kt < 64u){
      const bf16_t* src = A + (size_t)kt * 64;
      gload16(src + aoff[0], buf + ldst0);
      gload16(src + aoff[1], buf + ldst1);
    }
  };
  auto stgB = [&](char* buf, int kt, int pr){
    if ((unsigned)kt < 64u){
      const bf16_t* src = B + (size_t)kt * 64 + (size_t)pr * (32 * HID);
      char* dst = buf + 16384 + pr * 16384;
      gload16(src + boff[0], dst + ldst0);
      gload16(src + boff[1], dst + ldst1);
    }
  };

  const int koff0 = ((0 + g) ^ (lm & 7)) << 4;
  const int koff1 = ((4 + g) ^ (lm & 7)) << 4;
  const int abase = ((wr << 6) + lm) << 7;
  const int bbase = ((wc << 5) + lm) << 7;

  // prologue: A,B0,B1(0) [6 loads] + A,B0(1) [4 loads]; vmcnt(4) -> kt0 landed.
  stgA(buf0, 0); stgB(buf0, 0, 0); stgB(buf0, 0, 1);
  stgA(buf1, 1); stgB(buf1, 1, 0);
  asm volatile("s_waitcnt vmcnt(4)" ::: "memory");
  __builtin_amdgcn_s_barrier();

  bf16x8 afA[4][2], afB[4][2], bU[2][2], bV[2][2];
  RDA(afA, buf0)                 // A(0)
  RDB(bU, buf0, 16384)           // B0(0)

  for (int i = 0; i < 31; ++i){
    const int kt0 = 2 * i;
    // ---- P1 = ph1(kt0): MFMA A x B0; read B1(kt0); stage B1(kt0+1)->buf1 ----
    PTOPX(4)
    RDB(bV, buf0, 32768)
    stgB(buf1, kt0 + 1, 1);
    LGK(4)
    MM6(afA, bU, 0)
    // ---- P2 = ph2(kt0): MFMA A x B1; read A,B0(kt0+1); stage A,B0(kt0+2)->buf0 ----
    PTOPX(2)
    RDA(afB, buf1)
    RDB(bU, buf1, 16384)
    stgA(buf0, kt0 + 2); stgB(buf0, kt0 + 2, 0);
    LGK(12)
    MM6(afA, bV, 1)
    // ---- P3 = ph1(kt0+1): MFMA A' x B0'; read B1(kt0+1); stage B1(kt0+2)->buf0 ----
    PTOPX(4)
    RDB(bV, buf1, 32768)
    stgB(buf0, kt0 + 2, 1);
    LGK(4)
    MM6(afB, bU, 0)
    // ---- P4 = ph2(kt0+1): MFMA A' x B1'; read A,B0(kt0+2); stage A,B0(kt0+3)->buf1 ----
    PTOPX(2)
    RDA(afA, buf0)
    RDB(bU, buf0, 16384)
    stgA(buf1, kt0 + 3); stgB(buf1, kt0 + 3, 0);
    LGK(12)
    MM6(afB, bV, 1)
  }

  // ---- peeled tail: kt = 62, 63 ----
  PTOPX(4)                       // retires B1(62)
  RDB(bV, buf0, 32768)           // B1(62)
  stgB(buf1, 63, 1);             // B1(63)
  LGK(4)
  MM6(afA, bU, 0)
  PTOPX(2)                       // retires A,B0(63)
  RDA(afB, buf1)                 // A(63)
  RDB(bU, buf1, 16384)           // B0(63)
  LGK(12)
  MM6(afA, bV, 1)
  PTOPX(0)                       // retires B1(63)
  RDB(bV, buf1, 32768)           // B1(63)
  LGK(4)
  MM6(afB, bU, 0)
  LGK(0)
  MM6(afB, bV, 1)

  // epilogue: f32 out [T][HID]
#pragma unroll
  for (int pr = 0; pr < 2; ++pr)
#pragma unroll
    for (int ni = 0; ni < 2; ++ni){
      const int col = n0 + wc * 64 + pr * 32 + ni * 16 + lm;
      const int ai = pr * 2 + ni;
#pragma unroll
      for (int mf = 0; mf < 4; ++mf)
#pragma unroll
        for (int r = 0; r < 4; ++r){
          const int trow = m0 + wr * 64 + mf * 16 + g * 4 + r;
          OF[(size_t)trow * HID + col] = acc[mf][ai][r];
        }
    }
}

// ---------------- flash attention: 32x32 MFMA, counted-vmcnt KV pipeline ----------------
// R13: QK MFMA chain split — sacc[kvh] was an 8-deep serial accumulator chain (same C
// register across 8 MFMAs; chained latency ~2-3x the 8cy issue). Split into two 4-deep
// partials (dc 0-3 / 4-7) + one f32x16 vector add: halves critical depth for 16 v_add.
// Masked-path pm reduce also pairwise (v_max3), matching the unmasked path.
// R10/R11/R12-proven parts kept: krow&15 K-swizzle, V double-row layout, exp2_raw,
// tree-reduced sum, permlane32_swap exchange, shfl broadcast (no lred).
__global__ __launch_bounds__(256, 2) void attn2_k(
    const bf16_t* __restrict__ Q,
    const bf16_t* __restrict__ Kc,
    const bf16_t* __restrict__ VTc,
    const bf16_t* __restrict__ Kp,
    const bf16_t* __restrict__ VTp,
    bf16_t* __restrict__ Ctx,
    const int* __restrict__ plen_p,
    const int* __restrict__ pos)
{
  // XCD-chunked + complementary-qb balance remap (bijective, R8 version)
  const int bid = blockIdx.x;          // 0..511
  const int xcd = bid & 7;
  const int k   = bid >> 3;            // 0..63
  const int ho  = k >> 4;              // 0..3
  const int qraw= k & 15;
  const int h   = (xcd << 2) | ho;
  const int qb  = (ho & 2) ? (15 - qraw) : qraw;

  const int tid = threadIdx.x;
  const int w = tid >> 6, lane = tid & 63, l31 = lane & 31, hi = lane >> 5;
  const int qw0 = qb * 128 + w * 32;
  const int qrow = qw0 + l31;
  const int plen = plen_p[0];
  const int npast = (plen + 63) >> 6;
  const int NT = npast + 2 * qb + 2;

  __shared__ __align__(16) char smem[65536];

  // Q fragments from global; rope+scale in-register (consumes loads before stage(0))
  const bf16_t* qbase = Q + ((size_t)h * T_LEN + qrow) * DHEAD;
  bf16x8 qf[8];
#pragma unroll
  for (int dc = 0; dc < 8; ++dc)
    qf[dc] = *(const bf16x8*)(qbase + dc * 16 + 8 * hi);
  {
    const float ppos = (float)pos[qrow];
    const float qs = 0.12751744f;            // (1/sqrt(128)) * log2(e): exp2-domain scores
#pragma unroll
    for (int dc = 0; dc < 4; ++dc)
#pragma unroll
      for (int j = 0; j < 8; ++j){
        const int fi = dc * 16 + 8 * hi + j;               // freq index = d (< 64)
        const float invf = __expf(-(float)fi * 0.14391156605212898f);
        float sn, cs;
        sincosf(ppos * invf, &sn, &cs);
        const float a0 = (float)qf[dc][j], a1 = (float)qf[dc + 4][j];
        qf[dc][j]     = (bf16_t)((a0 * cs - a1 * sn) * qs);
        qf[dc + 4][j] = (bf16_t)((a1 * cs + a0 * sn) * qs);
      }
  }
  __builtin_amdgcn_sched_barrier(0);

  const f32x16 fz = {0.f,0.f,0.f,0.f,0.f,0.f,0.f,0.f,0.f,0.f,0.f,0.f,0.f,0.f,0.f,0.f};
  f32x16 o[4] = {fz, fz, fz, fz};
  float m = -1e30f, l = 0.f;

  auto stage = [&](int t, int buf){
    const bf16_t* kb; const bf16_t* vb;
    if (t < npast){
      const int s0 = t * 64;
      kb = Kp  + ((size_t)h * PAST_MAX + s0) * DHEAD;
      vb = VTp + (size_t)h * DHEAD * PAST_MAX + s0;
    } else {
      const int s0 = (t - npast) * 64;
      kb = Kc  + ((size_t)h * T_LEN + s0) * DHEAD;
      vb = VTc + (size_t)h * DHEAD * T_LEN + s0;
    }
    char* kl = smem + buf * 32768;
    char* vl = kl + 16384;
#pragma unroll
    for (int i = 0; i < 4; ++i){
      const int c = i * 256 + w * 64 + lane;
      const int krow = c >> 4, kcol = c & 15;          // K [64][128] bf16, 16 chunks/row
      gload16(kb + (size_t)krow * DHEAD + ((kcol ^ (krow & 15)) << 3), kl + (i * 256 + w * 64) * 16);
      // V^T double-row layout: dr = c>>4 (256B), phys slot s = c&15 holds logical
      // slot j = s ^ (dr&15); j -> row 2*dr + (j>>3), chunk j&7.
      const int vdr = c >> 4, vs = c & 15;
      const int vj = vs ^ (vdr & 15);
      gload16(vb + (size_t)(2 * vdr + (vj >> 3)) * 2048 + ((vj & 7) << 3), vl + (i * 256 + w * 64) * 16);
    }
  };

  stage(0, 0);
  __builtin_amdgcn_sched_barrier(0);

  for (int t = 0; t < NT; ++t){
    const int cur = t & 1;
    if (t + 1 < NT){
      stage(t + 1, cur ^ 1);
      asm volatile("s_waitcnt vmcnt(8)" ::: "memory");   // tile t landed; t+1 in flight
    } else {
      asm volatile("s_waitcnt vmcnt(0)" ::: "memory");
    }
    __builtin_amdgcn_sched_barrier(0);
    __builtin_amdgcn_s_barrier();
    __builtin_amdgcn_sched_barrier(0);

    const bool isc = (t >= npast);
    const int s0c = (t - npast) * 64;
    const bool active = !isc || (s0c <= qw0 + 31);

    if (active){
      char* kl = smem + cur * 32768;
      char* vl = kl + 16384;

      // QK^T: two 4-deep partial chains per kvh (halved dep depth), combined by vec add
      f32x16 sacc[2];
      __builtin_amdgcn_s_setprio(1);
#pragma unroll
      for (int kvh = 0; kvh < 2; ++kvh){
        const int krow = (kvh << 5) + l31;
        const int kbo = krow << 8;
        const int sw = (krow & 15) << 4;               // widened swizzle (R10-proven)
        f32x16 sa = fz, sb = fz;
#pragma unroll
        for (int dc = 0; dc < 4; ++dc){
          const bf16x8 kf = *(const bf16x8*)(kl + kbo + ((dc * 32 + 16 * hi) ^ sw));
          sa = __builtin_amdgcn_mfma_f32_32x32x16_bf16(kf, qf[dc], sa, 0, 0, 0);
        }
#pragma unroll
        for (int dc = 4; dc < 8; ++dc){
          const bf16x8 kf = *(const bf16x8*)(kl + kbo + ((dc * 32 + 16 * hi) ^ sw));
          sb = __builtin_amdgcn_mfma_f32_32x32x16_bf16(kf, qf[dc], sb, 0, 0, 0);
        }
        sacc[kvh] = sa + sb;
      }
      __builtin_amdgcn_s_setprio(0);

      // mask-hoist: only diagonal/boundary tiles pay the per-element mask chain
      const bool mcur  = isc && (s0c + 63 > qw0);
      const bool mpast = !isc && ((t + 1) * 64 > plen);
      float pv[2][16];
      float pm = -1e30f;
      if (mcur | mpast){
#pragma unroll
        for (int kvh = 0; kvh < 2; ++kvh)
#pragma unroll
          for (int r = 0; r < 16; r += 2){
            float x0 = sacc[kvh][r], x1 = sacc[kvh][r + 1];
            const int kv0 = (kvh << 5) + (r & 3) + 8 * (r >> 2) + 4 * hi;
            const int kv1 = (kvh << 5) + ((r + 1) & 3) + 8 * ((r + 1) >> 2) + 4 * hi;
            if (mcur  && (s0c + kv0 >  qrow)) x0 = -1e30f;
            if (mpast && (t * 64 + kv0 >= plen)) x0 = -1e30f;
            if (mcur  && (s0c + kv1 >  qrow)) x1 = -1e30f;
            if (mpast && (t * 64 + kv1 >= plen)) x1 = -1e30f;
            pv[kvh][r] = x0; pv[kvh][r + 1] = x1;
            pm = fmaxf(fmaxf(x0, x1), pm);             // -> v_max3
          }
      } else {
#pragma unroll
        for (int kvh = 0; kvh < 2; ++kvh)
#pragma unroll
          for (int r = 0; r < 16; r += 2){
            pv[kvh][r]     = sacc[kvh][r];
            pv[kvh][r + 1] = sacc[kvh][r + 1];
            pm = fmaxf(fmaxf(sacc[kvh][r], sacc[kvh][r + 1]), pm);   // -> v_max3
          }
      }
      pm = fmaxf(pm, __shfl_xor(pm, 32));

      // defer-max (log2 domain): rescale only when max grows past 11.5 ~= 8*log2e
      if (!__all(pm - m <= 11.5f)){
        const float mn = fmaxf(m, pm);
        const float corr = exp2_raw(m - mn);
        m = mn;
        l *= corr;
        // broadcast via lane read: lanes cr and cr+32 hold identical corr for row cr
#pragma unroll
        for (int r = 0; r < 16; ++r){
          const float cc = __shfl(corr, (r & 3) + 8 * (r >> 2) + 4 * hi);
#pragma unroll
          for (int nb = 0; nb < 4; ++nb) o[nb][r] *= cc;
        }
      }

      // exp + tree-reduced sum (4 partials, 2-level combine: ~8-deep chain not 32)
      float s4[4] = {0.f, 0.f, 0.f, 0.f};
#pragma unroll
      for (int kvh = 0; kvh < 2; ++kvh)
#pragma unroll
        for (int r = 0; r < 16; ++r){
          const float pe = exp2_raw(pv[kvh][r] - m);   // bare v_exp_f32
          pv[kvh][r] = pe;
          s4[r & 3] += pe;
        }
      float sum = (s4[0] + s4[1]) + (s4[2] + s4[3]);
      sum += __shfl_xor(sum, 32);
      l += sum;

      // pack own 32 P to 16 words; exchange halves -> PV A-frags
      unsigned wds[2][8];
#pragma unroll
      for (int kvh = 0; kvh < 2; ++kvh)
#pragma unroll
        for (int i = 0; i < 8; ++i)
          wds[kvh][i] = pack_bf16(pv[kvh][2 * i], pv[kvh][2 * i + 1]);

      bf16x8 pf[4];
#if __has_builtin(__builtin_amdgcn_permlane32_swap)
#pragma unroll
      for (int ks = 0; ks < 4; ++ks){
        const int s = ks & 1, kvh = ks >> 1;
        // (x',y') = swap(x,y): x'[i<32]=x[i], x'[32+i]=y[i]; y'[i<32]=x[32+i], y'[32+i]=y[32+i]
        u32x2 p02 = __builtin_amdgcn_permlane32_swap(wds[kvh][4*s],     wds[kvh][4*s + 2], false, false);
        u32x2 p13 = __builtin_amdgcn_permlane32_swap(wds[kvh][4*s + 1], wds[kvh][4*s + 3], false, false);
        u32x4 fw;
        fw[0] = p02[0]; fw[1] = p13[0]; fw[2] = p02[1]; fw[3] = p13[1];
        pf[ks] = __builtin_bit_cast(bf16x8, fw);
      }
#else
#pragma unroll
      for (int ks = 0; ks < 4; ++ks){
        const int s = ks & 1, kvh = ks >> 1;
        const unsigned a0 = hi ? wds[kvh][4 * s]     : wds[kvh][4 * s + 2];
        const unsigned a1 = hi ? wds[kvh][4 * s + 1] : wds[kvh][4 * s + 3];
        const unsigned z0 = (unsigned)__shfl_xor((int)a0, 32);
        const unsigned z1 = (unsigned)__shfl_xor((int)a1, 32);
        u32x4 fw;
        fw[0] = hi ? z0 : wds[kvh][4 * s];
        fw[1] = hi ? z1 : wds[kvh][4 * s + 1];
        fw[2] = hi ? wds[kvh][4 * s + 2] : z0;
        fw[3] = hi ? wds[kvh][4 * s + 3] : z1;
        pf[ks] = __builtin_bit_cast(bf16x8, fw);
      }
#endif

      // PV: O[q][dv] += P·V, V^T frags from LDS (double-row layout)
      __builtin_amdgcn_s_setprio(1);
#pragma unroll
      for (int ks = 0; ks < 4; ++ks)
#pragma unroll
        for (int nb = 0; nb < 4; ++nb){
          const int vrow = (nb << 5) + l31;
          const int vdr = vrow >> 1;
          const int j16 = ((vrow & 1) << 3) + 2 * ks + hi;
          const bf16x8 vf = *(const bf16x8*)(vl + (vdr << 8) + ((j16 ^ (vdr & 15)) << 4));
          o[nb] = __builtin_amdgcn_mfma_f32_32x32x16_bf16(pf[ks], vf, o[nb], 0, 0, 0);
        }
      __builtin_amdgcn_s_setprio(0);
    }
    __builtin_amdgcn_sched_barrier(0);
    __builtin_amdgcn_s_barrier();       // WAR release: buf cur free for t+2's stage
  }

  // epilogue: O / l -> Ctx [T][HID]; l broadcast via lane read (lanes cr/cr+32 identical)
#pragma unroll
  for (int r = 0; r < 16; ++r){
    const int cr = (r & 3) + 8 * (r >> 2) + 4 * hi;
    const float lrow = __shfl(l, cr);
    const float li = 1.f / lrow;
    const int trow = qw0 + cr;
    bf16_t* cb = Ctx + (size_t)trow * HID + h * DHEAD + l31;
#pragma unroll
    for (int nb = 0; nb < 4; ++nb)
      cb[nb << 5] = (bf16_t)(o[nb][r] * li);
  }
}

// ---------------- launcher ----------------
extern "C" void kernel_launch(void* const* d_in, const int* in_sizes, int n_in,
                              void* d_out, int out_size, void* d_ws, size_t ws_size,
                              hipStream_t stream)
{
  const float* X   = (const float*)d_in[0];
  const float* Wq  = (const float*)d_in[2];
  const float* Wk  = (const float*)d_in[3];
  const float* Wv  = (const float*)d_in[4];
  const float* Wo  = (const float*)d_in[5];
  const float* PKi = (const float*)d_in[6];
  const float* PVi = (const float*)d_in[7];
  const int* POS   = (const int*)d_in[8];
  const int* PLEN  = (const int*)d_in[9];
  float* OUT = (float*)d_out;

  char* ws = (char*)d_ws;
  const size_t SZ_XB  = (size_t)T_LEN * HID * 2;             // 16 MiB
  const size_t SZ_W   = (size_t)HID * HID * 2;               // 32 MiB
  const size_t SZ_HTD = (size_t)NHEAD * T_LEN * DHEAD * 2;   // 16 MiB

  bf16_t* XB  = (bf16_t*)(ws);
  bf16_t* WT0 = (bf16_t*)(ws + SZ_XB);                       // WT0|WT1|WT2 contiguous:
  bf16_t* WT1 = (bf16_t*)(ws + SZ_XB + SZ_W);                // concatenated B [12288][4096]
  bf16_t* WT2 = (bf16_t*)(ws + SZ_XB + 2 * SZ_W);
  char* p = ws + SZ_XB + 3 * SZ_W;
  bf16_t* QB   = (bf16_t*)p; p += SZ_HTD;
  bf16_t* KB   = (bf16_t*)p; p += SZ_HTD;
  bf16_t* VTB  = (bf16_t*)p; p += SZ_HTD;
  bf16_t* KPB  = (bf16_t*)p; p += SZ_HTD;
  bf16_t* VPTB = (bf16_t*)p; p += SZ_HTD;
  bf16_t* CTX  = (bf16_t*)p; p += SZ_HTD;
  bf16_t* WOT  = QB;   // reuse QB+KB (32 MiB contiguous) after attention

  dim3 blk256(256);
  dim3 blk512(512);
  cvt2_k<<<16384, blk256, 0, stream>>>(X, XB, PKi, KPB, T_LEN * HID / 4);
  transpose3_k<<<dim3(64,64,3), blk256, 0, stream>>>(Wq, Wk, Wv, WT0, WT1, WT2);
  transpose2_k<<<dim3(32,2,32), blk256, 0, stream>>>(PVi, VPTB, PAST_MAX, DHEAD);

  gemmqkv6p_k<<<512, blk512, 0, stream>>>(XB, WT0, QB, KB, VTB);
  ropek8_k<<<2048, blk256, 0, stream>>>(KB, POS);
  attn2_k<<<512, blk256, 0, stream>>>(QB, KB, VTB, KPB, VPTB, CTX, PLEN, POS);

  transpose2_k<<<dim3(64,64,1), blk256, 0, stream>>>(Wo, WOT, HID, HID);
  gemmop_ra_k<<<256, blk512, 0, stream>>>(CTX, WOT, OUT);
}

// Round 14
// 515.038 us; speedup vs baseline: 1.0075x; 1.0075x over previous
//
#include <hip/hip_runtime.h>
#include <cstdint>
#include <cstddef>

#define T_LEN 2048
#define PAST_MAX 2048
#define HID 4096
#define NHEAD 32
#define DHEAD 128

typedef __bf16 bf16_t;
typedef __bf16 bf16x4 __attribute__((ext_vector_type(4)));
typedef __bf16 bf16x8 __attribute__((ext_vector_type(8)));
typedef float  f32x4  __attribute__((ext_vector_type(4)));
typedef float  f32x16 __attribute__((ext_vector_type(16)));
typedef unsigned int u32x4 __attribute__((ext_vector_type(4)));
typedef unsigned int u32x2 __attribute__((ext_vector_type(2)));

__device__ __forceinline__ void gload16(const void* g, void* l){
  __builtin_amdgcn_global_load_lds((const __attribute__((address_space(1))) void*)g,
                                   (__attribute__((address_space(3))) void*)l,
                                   16, 0, 0);
}

__device__ __forceinline__ unsigned pack_bf16(float a, float b){
  const unsigned ua = __builtin_bit_cast(unsigned short, (bf16_t)a);
  const unsigned ub = __builtin_bit_cast(unsigned short, (bf16_t)b);
  return ua | (ub << 16);
}

// raw v_exp_f32 (exp2) — avoid OCML exp2f's edge-handling overhead (R10 lesson:
// VALUBusy 37->47% from library exp2f; __builtin/asm emits the bare instruction).
#if __has_builtin(__builtin_amdgcn_exp2f)
__device__ __forceinline__ float exp2_raw(float x){ return __builtin_amdgcn_exp2f(x); }
#else
__device__ __forceinline__ float exp2_raw(float x){
  float r; asm("v_exp_f32 %0, %1" : "=v"(r) : "v"(x)); return r;
}
#endif

// ---------------- fused f32 -> bf16 for X and past_k ----------------
__global__ void cvt2_k(const float* __restrict__ a, bf16_t* __restrict__ ao,
                       const float* __restrict__ b, bf16_t* __restrict__ bo, int n4){
  int i = blockIdx.x * 256 + threadIdx.x;
  if (i < n4){
    const float4 v = ((const float4*)a)[i];
    bf16x4 o = { (bf16_t)v.x, (bf16_t)v.y, (bf16_t)v.z, (bf16_t)v.w };
    ((bf16x4*)ao)[i] = o;
  } else {
    i -= n4;
    const float4 v = ((const float4*)b)[i];
    bf16x4 o = { (bf16_t)v.x, (bf16_t)v.y, (bf16_t)v.z, (bf16_t)v.w };
    ((bf16x4*)bo)[i] = o;
  }
}

// ---------------- f32 [B][R][C] -> bf16 [B][C][R], 64x64 tiles ----------------
__global__ __launch_bounds__(256) void transpose2_k(const float* __restrict__ in,
                                                    bf16_t* __restrict__ out, int R, int C){
  __shared__ float tile[64][65];
  const int r0 = blockIdx.x << 6, c0 = blockIdx.y << 6;
  const size_t bo = (size_t)blockIdx.z * (size_t)R * (size_t)C;
  const int tx = threadIdx.x & 15, ty = threadIdx.x >> 4;
#pragma unroll
  for (int k = 0; k < 4; ++k){
    const float4 v = *(const float4*)(in + bo + (size_t)(r0 + ty + 16*k) * C + c0 + tx*4);
    float* tp = &tile[ty + 16*k][tx*4];
    tp[0] = v.x; tp[1] = v.y; tp[2] = v.z; tp[3] = v.w;
  }
  __syncthreads();
  const int rr0 = (threadIdx.x & 7) * 8;
  const int ccb = threadIdx.x >> 3;     // 0..31
#pragma unroll
  for (int k = 0; k < 2; ++k){
    const int cc = ccb + 32*k;
    bf16x8 o;
#pragma unroll
    for (int j = 0; j < 8; ++j) o[j] = (bf16_t)tile[rr0 + j][cc];
    *(bf16x8*)(out + bo + (size_t)(c0 + cc) * R + r0 + rr0) = o;
  }
}

// ---------------- fused transpose of Wq/Wk/Wv (z selects) ----------------
__global__ __launch_bounds__(256) void transpose3_k(
    const float* __restrict__ s0, const float* __restrict__ s1, const float* __restrict__ s2,
    bf16_t* __restrict__ d0, bf16_t* __restrict__ d1, bf16_t* __restrict__ d2){
  __shared__ float tile[64][65];
  const float* in = (blockIdx.z == 0) ? s0 : (blockIdx.z == 1) ? s1 : s2;
  bf16_t* out = (blockIdx.z == 0) ? d0 : (blockIdx.z == 1) ? d1 : d2;
  const int r0 = blockIdx.x << 6, c0 = blockIdx.y << 6;
  const int tx = threadIdx.x & 15, ty = threadIdx.x >> 4;
#pragma unroll
  for (int k = 0; k < 4; ++k){
    const float4 v = *(const float4*)(in + (size_t)(r0 + ty + 16*k) * HID + c0 + tx*4);
    float* tp = &tile[ty + 16*k][tx*4];
    tp[0] = v.x; tp[1] = v.y; tp[2] = v.z; tp[3] = v.w;
  }
  __syncthreads();
  const int rr0 = (threadIdx.x & 7) * 8;
  const int ccb = threadIdx.x >> 3;
#pragma unroll
  for (int k = 0; k < 2; ++k){
    const int cc = ccb + 32*k;
    bf16x8 o;
#pragma unroll
    for (int j = 0; j < 8; ++j) o[j] = (bf16_t)tile[rr0 + j][cc];
    *(bf16x8*)(out + (size_t)(c0 + cc) * HID + r0 + rr0) = o;
  }
}

// -------- RoPE in place on K only, bf16x8-vectorized (Q roped in-register in attn) -----
__global__ void ropek8_k(bf16_t* __restrict__ K, const int* __restrict__ pos){
  const int idx = blockIdx.x * 256 + threadIdx.x;     // 2048*256 = 512K threads
  const int jc = idx & 7;                             // 8-elem chunk within d<64
  const int t  = (idx >> 3) & (T_LEN - 1);
  const int h  = idx >> 14;
  const size_t base = ((size_t)h * T_LEN + t) * DHEAD;
  const float p = (float)pos[t];
  bf16x8 lo = *(bf16x8*)(K + base + jc * 8);
  bf16x8 hi = *(bf16x8*)(K + base + 64 + jc * 8);
  bf16x8 olo, ohi;
#pragma unroll
  for (int j = 0; j < 8; ++j){
    const int fi = jc * 8 + j;
    const float invf = __expf(-(float)fi * 0.14391156605212898f);  // ln(10000)/64
    float sn, cs;
    sincosf(p * invf, &sn, &cs);
    const float b0 = (float)lo[j], b1 = (float)hi[j];
    olo[j] = (bf16_t)(b0 * cs - b1 * sn);
    ohi[j] = (bf16_t)(b1 * cs + b0 * sn);
  }
  *(bf16x8*)(K + base + jc * 8) = olo;
  *(bf16x8*)(K + base + 64 + jc * 8) = ohi;
}

// ===================== shared schedule macros (R8-proven) ==============================
#define MM6(AF, BF, PR) \
  __builtin_amdgcn_s_setprio(1); \
  _Pragma("unroll") \
  for (int kk = 0; kk < 2; ++kk){ \
    _Pragma("unroll") \
    for (int mf = 0; mf < 4; ++mf){ \
      _Pragma("unroll") \
      for (int ni = 0; ni < 2; ++ni) \
        acc[mf][(PR)*2 + ni] = __builtin_amdgcn_mfma_f32_16x16x32_bf16( \
            AF[mf][kk], BF[ni][kk], acc[mf][(PR)*2 + ni], 0, 0, 0); \
    } \
  } \
  __builtin_amdgcn_s_setprio(0); \
  __builtin_amdgcn_sched_barrier(0);

#define RDA(SET, BUF) \
  _Pragma("unroll") \
  for (int mf = 0; mf < 4; ++mf){ \
    SET[mf][0] = *(const bf16x8*)((BUF) + abase + mf * 2048 + koff0); \
    SET[mf][1] = *(const bf16x8*)((BUF) + abase + mf * 2048 + koff1); \
  }

#define RDB(SET, BUF, UOFF) \
  _Pragma("unroll") \
  for (int ni = 0; ni < 2; ++ni){ \
    SET[ni][0] = *(const bf16x8*)((BUF) + (UOFF) + bbase + ni * 2048 + koff0); \
    SET[ni][1] = *(const bf16x8*)((BUF) + (UOFF) + bbase + ni * 2048 + koff1); \
  }

#define PTOPX(N) \
  asm volatile("s_waitcnt vmcnt(" #N ")" ::: "memory"); \
  __builtin_amdgcn_s_barrier(); \
  __builtin_amdgcn_sched_barrier(0);

#define LGK(N) \
  __builtin_amdgcn_sched_barrier(0); \
  asm volatile("s_waitcnt lgkmcnt(" #N ")" ::: "memory"); \
  __builtin_amdgcn_sched_barrier(0);

// ========= QKV: 128x384 BK=64, cross-phase read-ahead + counted lgkm (R8-proven) =======
// 189 us, MfmaUtil 49%. Unchanged.
__global__ __launch_bounds__(512, 1) void gemmqkv6p_k(
    const bf16_t* __restrict__ A,
    const bf16_t* __restrict__ Bc,       // concatenated W^T: [12288][4096]
    bf16_t* __restrict__ OQ, bf16_t* __restrict__ OK2, bf16_t* __restrict__ OVT)
{
  const int bid = blockIdx.x;
  const int wg  = (bid & 7) * 64 + (bid >> 3);   // 512 % 8 == 0 -> bijective XCD chunking
  const int mt  = wg & 15;                        // 16 M-tiles of 128
  const int nt  = wg >> 4;                        // 32 N-tiles of 384
  const int m0  = mt << 7;
  const int n0g = nt * 384;

  const int tid = threadIdx.x;
  const int wv = tid >> 6, lane = tid & 63, lm = lane & 15, g = lane >> 4;
  const int wr = wv >> 2, wc = wv & 3;   // 2 M-groups x 4 N-groups (wave tile 64x96)

  __shared__ __align__(16) char smem[131072];  // [buf][ A 16K | B0 16K | B1 16K | B2 16K ]
  char* const buf0 = smem;            // even K-tiles
  char* const buf1 = smem + 65536;    // odd K-tiles

  const f32x4 fzero = {0.f, 0.f, 0.f, 0.f};
  f32x4 acc[4][6];
#pragma unroll
  for (int i = 0; i < 4; ++i)
#pragma unroll
    for (int j = 0; j < 6; ++j) acc[i][j] = fzero;

  // staging decode: unit = 1024 chunks of 16B, 8 chunks per 128B row; source pre-swizzled
  size_t aoff[2], boff[2];
#pragma unroll
  for (int i = 0; i < 2; ++i){
    const int c = i * 512 + tid;
    const int u = c >> 3;                       // row-within-unit 0..127
    const int j = ((c & 7) ^ (u & 7)) << 3;     // element offset of 16B chunk
    aoff[i] = (size_t)(m0 + u) * HID + j;
    const int bcol = (u >> 5) * 96 + (u & 31);  // + pr*32 at call
    boff[i] = (size_t)(n0g + bcol) * HID + j;
  }
  const int ldst0 = (wv * 64) << 4;
  const int ldst1 = (512 + wv * 64) << 4;

  auto stgA = [&](char* buf, int kt){
    if ((unsigned)kt < 64u){
      const bf16_t* src = A + (size_t)kt * 64;
      gload16(src + aoff[0], buf + ldst0);
      gload16(src + aoff[1], buf + ldst1);
    }
  };
  auto stgB = [&](char* buf, int kt, int pr){
    if ((unsigned)kt < 64u){
      const bf16_t* src = Bc + (size_t)kt * 64 + (size_t)pr * (32 * HID);
      char* dst = buf + 16384 + pr * 16384;
      gload16(src + boff[0], dst + ldst0);
      gload16(src + boff[1], dst + ldst1);
    }
  };

  // fragment read constants (frag rows == lm mod 8 -> lane-constant swizzle)
  const int koff0 = ((0 + g) ^ (lm & 7)) << 4;
  const int koff1 = ((4 + g) ^ (lm & 7)) << 4;
  const int abase = ((wr << 6) + lm) << 7;      // + mf*2048
  const int bbase = ((wc << 5) + lm) << 7;      // + ni*2048 (within unit)

  // prologue: kt0 fully (loads 1-8), kt1 {A,B0,B1} (loads 9-14); vmcnt(6) -> kt0 done.
  stgA(buf0, 0); stgB(buf0, 0, 0); stgB(buf0, 0, 1); stgB(buf0, 0, 2);
  stgA(buf1, 1); stgB(buf1, 1, 0); stgB(buf1, 1, 1);
  asm volatile("s_waitcnt vmcnt(6)" ::: "memory");
  __builtin_amdgcn_s_barrier();

  bf16x8 afA[4][2], afB[4][2], bU[2][2], bV[2][2];
  RDA(afA, buf0)                 // A(0)
  RDB(bU, buf0, 16384)           // B0(0)

  for (int i = 0; i < 31; ++i){
    const int kt0 = 2 * i;
    // ---- P1 = ph1(kt0): MFMA A x B0; read B1(kt0); stage B2(kt0+1) ----
    PTOPX(8)
    RDB(bV, buf0, 32768)
    stgB(buf1, kt0 + 1, 2);
    LGK(4)
    MM6(afA, bU, 0)
    // ---- P2 = ph2(kt0): MFMA A x B1; read B2(kt0); stage A,B0(kt0+2) ----
    PTOPX(8)
    RDB(bU, buf0, 49152)
    stgA(buf0, kt0 + 2); stgB(buf0, kt0 + 2, 0);
    LGK(4)
    MM6(afA, bV, 1)
    // ---- P3 = ph3(kt0): MFMA A x B2; read A,B0(kt0+1); stage B1(kt0+2) ----
    PTOPX(8)
    RDA(afB, buf1)
    RDB(bV, buf1, 16384)
    stgB(buf0, kt0 + 2, 1);
    LGK(12)
    MM6(afA, bU, 2)
    // ---- P4 = ph1(kt0+1): MFMA A' x B0'; read B1(kt0+1); stage B2(kt0+2) ----
    PTOPX(8)
    RDB(bU, buf1, 32768)
    stgB(buf0, kt0 + 2, 2);
    LGK(4)
    MM6(afB, bV, 0)
    // ---- P5 = ph2(kt0+1): MFMA A' x B1'; read B2(kt0+1); stage A,B0(kt0+3) ----
    PTOPX(8)
    RDB(bV, buf1, 49152)
    stgA(buf1, kt0 + 3); stgB(buf1, kt0 + 3, 0);
    LGK(4)
    MM6(afB, bU, 1)
    // ---- P6 = ph3(kt0+1): MFMA A' x B2'; read A,B0(kt0+2); stage B1(kt0+3) ----
    PTOPX(8)
    RDA(afA, buf0)
    RDB(bU, buf0, 16384)
    stgB(buf1, kt0 + 3, 1);
    LGK(12)
    MM6(afB, bV, 2)
  }

  // ---- peeled final iteration: kt = 62, 63 (fully drained phase tops, no stages) ----
  PTOPX(0)
  RDB(bV, buf0, 32768)           // B1(62)
  stgB(buf1, 63, 2);             // B2(63)
  LGK(4)
  MM6(afA, bU, 0)
  PTOPX(0)
  RDB(bU, buf0, 49152)           // B2(62)
  LGK(4)
  MM6(afA, bV, 1)
  PTOPX(0)
  RDA(afB, buf1)                 // A(63)
  RDB(bV, buf1, 16384)           // B0(63)
  LGK(12)
  MM6(afA, bU, 2)
  PTOPX(0)
  RDB(bU, buf1, 32768)           // B1(63)
  LGK(4)
  MM6(afB, bV, 0)
  PTOPX(0)
  RDB(bV, buf1, 49152)           // B2(63)
  LGK(4)
  MM6(afB, bU, 1)
  LGK(0)
  MM6(afB, bV, 2)

  // epilogue: per-16-col-block z select (blocks never straddle 4096 boundaries)
#pragma unroll
  for (int pr = 0; pr < 3; ++pr)
#pragma unroll
    for (int ni = 0; ni < 2; ++ni){
      const int colg = n0g + wc * 96 + pr * 32 + ni * 16 + lm;
      const int z  = colg >> 12;
      const int wi = colg & 4095;
      const int hh = wi >> 7, dd = wi & 127;
      const int ai = pr * 2 + ni;
#pragma unroll
      for (int mf = 0; mf < 4; ++mf){
        const int trow0 = m0 + wr * 64 + mf * 16 + g * 4;
        if (z == 2){
          bf16x4 v4 = { (bf16_t)acc[mf][ai][0], (bf16_t)acc[mf][ai][1],
                        (bf16_t)acc[mf][ai][2], (bf16_t)acc[mf][ai][3] };
          *(bf16x4*)(OVT + ((size_t)hh * DHEAD + dd) * T_LEN + trow0) = v4;
        } else {
          bf16_t* ob = z ? OK2 : OQ;
#pragma unroll
          for (int r = 0; r < 4; ++r)
            ob[((size_t)hh * T_LEN + trow0 + r) * DHEAD + dd] = (bf16_t)acc[mf][ai][r];
        }
      }
    }
}

// ====== out-proj: 128x256 BK=64, cross-phase read-ahead port (R8 schedule, 2-phase) ====
__global__ __launch_bounds__(512, 1) void gemmop_ra_k(
    const bf16_t* __restrict__ A, const bf16_t* __restrict__ B,
    float* __restrict__ OF)
{
  const int bid = blockIdx.x;
  const int wg  = (bid & 7) * 32 + (bid >> 3);   // 256 % 8 == 0 -> bijective
  const int mt  = wg & 15;                        // 16 M-tiles of 128
  const int nt  = wg >> 4;                        // 16 N-tiles of 256
  const int m0  = mt << 7;
  const int n0  = nt << 8;

  const int tid = threadIdx.x;
  const int wv = tid >> 6, lane = tid & 63, lm = lane & 15, g = lane >> 4;
  const int wr = wv >> 2, wc = wv & 3;   // 2 M-groups x 4 N-groups (wave tile 64x64)

  __shared__ __align__(16) char smem[98304];   // [buf][ A 16K | B0 16K | B1 16K ]
  char* const buf0 = smem;
  char* const buf1 = smem + 49152;

  const f32x4 fzero = {0.f, 0.f, 0.f, 0.f};
  f32x4 acc[4][4];
#pragma unroll
  for (int i = 0; i < 4; ++i)
#pragma unroll
    for (int j = 0; j < 4; ++j) acc[i][j] = fzero;

  size_t aoff[2], boff[2];
#pragma unroll
  for (int i = 0; i < 2; ++i){
    const int c = i * 512 + tid;
    const int u = c >> 3;
    const int j = ((c & 7) ^ (u & 7)) << 3;
    aoff[i] = (size_t)(m0 + u) * HID + j;
    const int bcol = (u >> 5) * 64 + (u & 31);  // + pr*32 at call
    boff[i] = (size_t)(n0 + bcol) * HID + j;
  }
  const int ldst0 = (wv * 64) << 4;
  const int ldst1 = (512 + wv * 64) << 4;

  auto stgA = [&](char* buf, int kt){
    if ((unsigned)kt < 64u){
      const bf16_t* src = A + (size_t)kt * 64;
      gload16(src + aoff[0], buf + ldst0);
      gload16(src + aoff[1], buf + ldst1);
    }
  };
  auto stgB = [&](char* buf, int kt, int pr){
    if ((unsigned)kt < 64u){
      const bf16_t* src = B + (size_t)kt * 64 + (size_t)pr * (32 * HID);
      char* dst = buf + 16384 + pr * 16384;
      gload16(src + boff[0], dst + ldst0);
      gload16(src + boff[1], dst + ldst1);
    }
  };

  const int koff0 = ((0 + g) ^ (lm & 7)) << 4;
  const int koff1 = ((4 + g) ^ (lm & 7)) << 4;
  const int abase = ((wr << 6) + lm) << 7;
  const int bbase = ((wc << 5) + lm) << 7;

  // prologue: A,B0,B1(0) [6 loads] + A,B0(1) [4 loads]; vmcnt(4) -> kt0 landed.
  stgA(buf0, 0); stgB(buf0, 0, 0); stgB(buf0, 0, 1);
  stgA(buf1, 1); stgB(buf1, 1, 0);
  asm volatile("s_waitcnt vmcnt(4)" ::: "memory");
  __builtin_amdgcn_s_barrier();

  bf16x8 afA[4][2], afB[4][2], bU[2][2], bV[2][2];
  RDA(afA, buf0)                 // A(0)
  RDB(bU, buf0, 16384)           // B0(0)

  for (int i = 0; i < 31; ++i){
    const int kt0 = 2 * i;
    // ---- P1 = ph1(kt0): MFMA A x B0; read B1(kt0); stage B1(kt0+1)->buf1 ----
    PTOPX(4)
    RDB(bV, buf0, 32768)
    stgB(buf1, kt0 + 1, 1);
    LGK(4)
    MM6(afA, bU, 0)
    // ---- P2 = ph2(kt0): MFMA A x B1; read A,B0(kt0+1); stage A,B0(kt0+2)->buf0 ----
    PTOPX(2)
    RDA(afB, buf1)
    RDB(bU, buf1, 16384)
    stgA(buf0, kt0 + 2); stgB(buf0, kt0 + 2, 0);
    LGK(12)
    MM6(afA, bV, 1)
    // ---- P3 = ph1(kt0+1): MFMA A' x B0'; read B1(kt0+1); stage B1(kt0+2)->buf0 ----
    PTOPX(4)
    RDB(bV, buf1, 32768)
    stgB(buf0, kt0 + 2, 1);
    LGK(4)
    MM6(afB, bU, 0)
    // ---- P4 = ph2(kt0+1): MFMA A' x B1'; read A,B0(kt0+2); stage A,B0(kt0+3)->buf1 ----
    PTOPX(2)
    RDA(afA, buf0)
    RDB(bU, buf0, 16384)
    stgA(buf1, kt0 + 3); stgB(buf1, kt0 + 3, 0);
    LGK(12)
    MM6(afB, bV, 1)
  }

  // ---- peeled tail: kt = 62, 63 ----
  PTOPX(4)                       // retires B1(62)
  RDB(bV, buf0, 32768)           // B1(62)
  stgB(buf1, 63, 1);             // B1(63)
  LGK(4)
  MM6(afA, bU, 0)
  PTOPX(2)                       // retires A,B0(63)
  RDA(afB, buf1)                 // A(63)
  RDB(bU, buf1, 16384)           // B0(63)
  LGK(12)
  MM6(afA, bV, 1)
  PTOPX(0)                       // retires B1(63)
  RDB(bV, buf1, 32768)           // B1(63)
  LGK(4)
  MM6(afB, bU, 0)
  LGK(0)
  MM6(afB, bV, 1)

  // epilogue: f32 out [T][HID]
#pragma unroll
  for (int pr = 0; pr < 2; ++pr)
#pragma unroll
    for (int ni = 0; ni < 2; ++ni){
      const int col = n0 + wc * 64 + pr * 32 + ni * 16 + lm;
      const int ai = pr * 2 + ni;
#pragma unroll
      for (int mf = 0; mf < 4; ++mf)
#pragma unroll
        for (int r = 0; r < 4; ++r){
          const int trow = m0 + wr * 64 + mf * 16 + g * 4 + r;
          OF[(size_t)trow * HID + col] = acc[mf][ai][r];
        }
    }
}

// ---------------- flash attention: 32x32 MFMA, counted-vmcnt KV pipeline ----------------
// R14 = R12-proven version (session best 515.4 us). R13's QK chain-split measured
// neutral-to-negative (pre-committed revert): the 8-deep MFMA chain was already hidden
// by TLP; the split's extra v_adds + register pressure outweighed it.
// Proven parts: krow&15 K-swizzle (R10), V double-row layout + exp2_raw (R11),
// tree-reduced sum + permlane32_swap exchange + shfl broadcast (R12).
__global__ __launch_bounds__(256, 2) void attn2_k(
    const bf16_t* __restrict__ Q,
    const bf16_t* __restrict__ Kc,
    const bf16_t* __restrict__ VTc,
    const bf16_t* __restrict__ Kp,
    const bf16_t* __restrict__ VTp,
    bf16_t* __restrict__ Ctx,
    const int* __restrict__ plen_p,
    const int* __restrict__ pos)
{
  // XCD-chunked + complementary-qb balance remap (bijective, R8 version)
  const int bid = blockIdx.x;          // 0..511
  const int xcd = bid & 7;
  const int k   = bid >> 3;            // 0..63
  const int ho  = k >> 4;              // 0..3
  const int qraw= k & 15;
  const int h   = (xcd << 2) | ho;
  const int qb  = (ho & 2) ? (15 - qraw) : qraw;

  const int tid = threadIdx.x;
  const int w = tid >> 6, lane = tid & 63, l31 = lane & 31, hi = lane >> 5;
  const int qw0 = qb * 128 + w * 32;
  const int qrow = qw0 + l31;
  const int plen = plen_p[0];
  const int npast = (plen + 63) >> 6;
  const int NT = npast + 2 * qb + 2;

  __shared__ __align__(16) char smem[65536];

  // Q fragments from global; rope+scale in-register (consumes loads before stage(0))
  const bf16_t* qbase = Q + ((size_t)h * T_LEN + qrow) * DHEAD;
  bf16x8 qf[8];
#pragma unroll
  for (int dc = 0; dc < 8; ++dc)
    qf[dc] = *(const bf16x8*)(qbase + dc * 16 + 8 * hi);
  {
    const float ppos = (float)pos[qrow];
    const float qs = 0.12751744f;            // (1/sqrt(128)) * log2(e): exp2-domain scores
#pragma unroll
    for (int dc = 0; dc < 4; ++dc)
#pragma unroll
      for (int j = 0; j < 8; ++j){
        const int fi = dc * 16 + 8 * hi + j;               // freq index = d (< 64)
        const float invf = __expf(-(float)fi * 0.14391156605212898f);
        float sn, cs;
        sincosf(ppos * invf, &sn, &cs);
        const float a0 = (float)qf[dc][j], a1 = (float)qf[dc + 4][j];
        qf[dc][j]     = (bf16_t)((a0 * cs - a1 * sn) * qs);
        qf[dc + 4][j] = (bf16_t)((a1 * cs + a0 * sn) * qs);
      }
  }
  __builtin_amdgcn_sched_barrier(0);

  const f32x16 fz = {0.f,0.f,0.f,0.f,0.f,0.f,0.f,0.f,0.f,0.f,0.f,0.f,0.f,0.f,0.f,0.f};
  f32x16 o[4] = {fz, fz, fz, fz};
  float m = -1e30f, l = 0.f;

  auto stage = [&](int t, int buf){
    const bf16_t* kb; const bf16_t* vb;
    if (t < npast){
      const int s0 = t * 64;
      kb = Kp  + ((size_t)h * PAST_MAX + s0) * DHEAD;
      vb = VTp + (size_t)h * DHEAD * PAST_MAX + s0;
    } else {
      const int s0 = (t - npast) * 64;
      kb = Kc  + ((size_t)h * T_LEN + s0) * DHEAD;
      vb = VTc + (size_t)h * DHEAD * T_LEN + s0;
    }
    char* kl = smem + buf * 32768;
    char* vl = kl + 16384;
#pragma unroll
    for (int i = 0; i < 4; ++i){
      const int c = i * 256 + w * 64 + lane;
      const int krow = c >> 4, kcol = c & 15;          // K [64][128] bf16, 16 chunks/row
      gload16(kb + (size_t)krow * DHEAD + ((kcol ^ (krow & 15)) << 3), kl + (i * 256 + w * 64) * 16);
      // V^T double-row layout: dr = c>>4 (256B), phys slot s = c&15 holds logical
      // slot j = s ^ (dr&15); j -> row 2*dr + (j>>3), chunk j&7.
      const int vdr = c >> 4, vs = c & 15;
      const int vj = vs ^ (vdr & 15);
      gload16(vb + (size_t)(2 * vdr + (vj >> 3)) * 2048 + ((vj & 7) << 3), vl + (i * 256 + w * 64) * 16);
    }
  };

  stage(0, 0);
  __builtin_amdgcn_sched_barrier(0);

  for (int t = 0; t < NT; ++t){
    const int cur = t & 1;
    if (t + 1 < NT){
      stage(t + 1, cur ^ 1);
      asm volatile("s_waitcnt vmcnt(8)" ::: "memory");   // tile t landed; t+1 in flight
    } else {
      asm volatile("s_waitcnt vmcnt(0)" ::: "memory");
    }
    __builtin_amdgcn_sched_barrier(0);
    __builtin_amdgcn_s_barrier();
    __builtin_amdgcn_sched_barrier(0);

    const bool isc = (t >= npast);
    const int s0c = (t - npast) * 64;
    const bool active = !isc || (s0c <= qw0 + 31);

    if (active){
      char* kl = smem + cur * 32768;
      char* vl = kl + 16384;

      f32x16 sacc[2] = {fz, fz};
      __builtin_amdgcn_s_setprio(1);
#pragma unroll
      for (int kvh = 0; kvh < 2; ++kvh){
        const int krow = (kvh << 5) + l31;
        const int kbo = krow << 8;
        const int sw = (krow & 15) << 4;               // widened swizzle (R10-proven)
#pragma unroll
        for (int dc = 0; dc < 8; ++dc){
          const bf16x8 kf = *(const bf16x8*)(kl + kbo + ((dc * 32 + 16 * hi) ^ sw));
          sacc[kvh] = __builtin_amdgcn_mfma_f32_32x32x16_bf16(kf, qf[dc], sacc[kvh], 0, 0, 0);
        }
      }
      __builtin_amdgcn_s_setprio(0);

      // mask-hoist: only diagonal/boundary tiles pay the per-element mask chain
      const bool mcur  = isc && (s0c + 63 > qw0);
      const bool mpast = !isc && ((t + 1) * 64 > plen);
      float pv[2][16];
      float pm = -1e30f;
      if (mcur | mpast){
#pragma unroll
        for (int kvh = 0; kvh < 2; ++kvh)
#pragma unroll
          for (int r = 0; r < 16; ++r){
            float x = sacc[kvh][r];
            const int kvoff = (kvh << 5) + (r & 3) + 8 * (r >> 2) + 4 * hi;
            if (mcur  && (s0c + kvoff >  qrow)) x = -1e30f;
            if (mpast && (t * 64 + kvoff >= plen)) x = -1e30f;
            pv[kvh][r] = x;
            pm = fmaxf(pm, x);
          }
      } else {
#pragma unroll
        for (int kvh = 0; kvh < 2; ++kvh)
#pragma unroll
          for (int r = 0; r < 16; r += 2){
            pv[kvh][r]     = sacc[kvh][r];
            pv[kvh][r + 1] = sacc[kvh][r + 1];
            pm = fmaxf(fmaxf(sacc[kvh][r], sacc[kvh][r + 1]), pm);   // -> v_max3
          }
      }
      pm = fmaxf(pm, __shfl_xor(pm, 32));

      // defer-max (log2 domain): rescale only when max grows past 11.5 ~= 8*log2e
      if (!__all(pm - m <= 11.5f)){
        const float mn = fmaxf(m, pm);
        const float corr = exp2_raw(m - mn);
        m = mn;
        l *= corr;
        // broadcast via lane read: lanes cr and cr+32 hold identical corr for row cr
#pragma unroll
        for (int r = 0; r < 16; ++r){
          const float cc = __shfl(corr, (r & 3) + 8 * (r >> 2) + 4 * hi);
#pragma unroll
          for (int nb = 0; nb < 4; ++nb) o[nb][r] *= cc;
        }
      }

      // exp + tree-reduced sum (4 partials, 2-level combine: ~8-deep chain not 32)
      float s4[4] = {0.f, 0.f, 0.f, 0.f};
#pragma unroll
      for (int kvh = 0; kvh < 2; ++kvh)
#pragma unroll
        for (int r = 0; r < 16; ++r){
          const float pe = exp2_raw(pv[kvh][r] - m);   // bare v_exp_f32
          pv[kvh][r] = pe;
          s4[r & 3] += pe;
        }
      float sum = (s4[0] + s4[1]) + (s4[2] + s4[3]);
      sum += __shfl_xor(sum, 32);
      l += sum;

      // pack own 32 P to 16 words; exchange halves -> PV A-frags
      unsigned wds[2][8];
#pragma unroll
      for (int kvh = 0; kvh < 2; ++kvh)
#pragma unroll
        for (int i = 0; i < 8; ++i)
          wds[kvh][i] = pack_bf16(pv[kvh][2 * i], pv[kvh][2 * i + 1]);

      bf16x8 pf[4];
#if __has_builtin(__builtin_amdgcn_permlane32_swap)
#pragma unroll
      for (int ks = 0; ks < 4; ++ks){
        const int s = ks & 1, kvh = ks >> 1;
        // (x',y') = swap(x,y): x'[i<32]=x[i], x'[32+i]=y[i]; y'[i<32]=x[32+i], y'[32+i]=y[32+i]
        u32x2 p02 = __builtin_amdgcn_permlane32_swap(wds[kvh][4*s],     wds[kvh][4*s + 2], false, false);
        u32x2 p13 = __builtin_amdgcn_permlane32_swap(wds[kvh][4*s + 1], wds[kvh][4*s + 3], false, false);
        u32x4 fw;
        fw[0] = p02[0]; fw[1] = p13[0]; fw[2] = p02[1]; fw[3] = p13[1];
        pf[ks] = __builtin_bit_cast(bf16x8, fw);
      }
#else
#pragma unroll
      for (int ks = 0; ks < 4; ++ks){
        const int s = ks & 1, kvh = ks >> 1;
        const unsigned a0 = hi ? wds[kvh][4 * s]     : wds[kvh][4 * s + 2];
        const unsigned a1 = hi ? wds[kvh][4 * s + 1] : wds[kvh][4 * s + 3];
        const unsigned z0 = (unsigned)__shfl_xor((int)a0, 32);
        const unsigned z1 = (unsigned)__shfl_xor((int)a1, 32);
        u32x4 fw;
        fw[0] = hi ? z0 : wds[kvh][4 * s];
        fw[1] = hi ? z1 : wds[kvh][4 * s + 1];
        fw[2] = hi ? wds[kvh][4 * s + 2] : z0;
        fw[3] = hi ? wds[kvh][4 * s + 3] : z1;
        pf[ks] = __builtin_bit_cast(bf16x8, fw);
      }
#endif

      // PV: O[q][dv] += P·V, V^T frags from LDS (double-row layout)
      __builtin_amdgcn_s_setprio(1);
#pragma unroll
      for (int ks = 0; ks < 4; ++ks)
#pragma unroll
        for (int nb = 0; nb < 4; ++nb){
          const int vrow = (nb << 5) + l31;
          const int vdr = vrow >> 1;
          const int j16 = ((vrow & 1) << 3) + 2 * ks + hi;
          const bf16x8 vf = *(const bf16x8*)(vl + (vdr << 8) + ((j16 ^ (vdr & 15)) << 4));
          o[nb] = __builtin_amdgcn_mfma_f32_32x32x16_bf16(pf[ks], vf, o[nb], 0, 0, 0);
        }
      __builtin_amdgcn_s_setprio(0);
    }
    __builtin_amdgcn_sched_barrier(0);
    __builtin_amdgcn_s_barrier();       // WAR release: buf cur free for t+2's stage
  }

  // epilogue: O / l -> Ctx [T][HID]; l broadcast via lane read (lanes cr/cr+32 identical)
#pragma unroll
  for (int r = 0; r < 16; ++r){
    const int cr = (r & 3) + 8 * (r >> 2) + 4 * hi;
    const float lrow = __shfl(l, cr);
    const float li = 1.f / lrow;
    const int trow = qw0 + cr;
    bf16_t* cb = Ctx + (size_t)trow * HID + h * DHEAD + l31;
#pragma unroll
    for (int nb = 0; nb < 4; ++nb)
      cb[nb << 5] = (bf16_t)(o[nb][r] * li);
  }
}

// ---------------- launcher ----------------
extern "C" void kernel_launch(void* const* d_in, const int* in_sizes, int n_in,
                              void* d_out, int out_size, void* d_ws, size_t ws_size,
                              hipStream_t stream)
{
  const float* X   = (const float*)d_in[0];
  const float* Wq  = (const float*)d_in[2];
  const float* Wk  = (const float*)d_in[3];
  const float* Wv  = (const float*)d_in[4];
  const float* Wo  = (const float*)d_in[5];
  const float* PKi = (const float*)d_in[6];
  const float* PVi = (const float*)d_in[7];
  const int* POS   = (const int*)d_in[8];
  const int* PLEN  = (const int*)d_in[9];
  float* OUT = (float*)d_out;

  char* ws = (char*)d_ws;
  const size_t SZ_XB  = (size_t)T_LEN * HID * 2;             // 16 MiB
  const size_t SZ_W   = (size_t)HID * HID * 2;               // 32 MiB
  const size_t SZ_HTD = (size_t)NHEAD * T_LEN * DHEAD * 2;   // 16 MiB

  bf16_t* XB  = (bf16_t*)(ws);
  bf16_t* WT0 = (bf16_t*)(ws + SZ_XB);                       // WT0|WT1|WT2 contiguous:
  bf16_t* WT1 = (bf16_t*)(ws + SZ_XB + SZ_W);                // concatenated B [12288][4096]
  bf16_t* WT2 = (bf16_t*)(ws + SZ_XB + 2 * SZ_W);
  char* p = ws + SZ_XB + 3 * SZ_W;
  bf16_t* QB   = (bf16_t*)p; p += SZ_HTD;
  bf16_t* KB   = (bf16_t*)p; p += SZ_HTD;
  bf16_t* VTB  = (bf16_t*)p; p += SZ_HTD;
  bf16_t* KPB  = (bf16_t*)p; p += SZ_HTD;
  bf16_t* VPTB = (bf16_t*)p; p += SZ_HTD;
  bf16_t* CTX  = (bf16_t*)p; p += SZ_HTD;
  bf16_t* WOT  = QB;   // reuse QB+KB (32 MiB contiguous) after attention

  dim3 blk256(256);
  dim3 blk512(512);
  cvt2_k<<<16384, blk256, 0, stream>>>(X, XB, PKi, KPB, T_LEN * HID / 4);
  transpose3_k<<<dim3(64,64,3), blk256, 0, stream>>>(Wq, Wk, Wv, WT0, WT1, WT2);
  transpose2_k<<<dim3(32,2,32), blk256, 0, stream>>>(PVi, VPTB, PAST_MAX, DHEAD);

  gemmqkv6p_k<<<512, blk512, 0, stream>>>(XB, WT0, QB, KB, VTB);
  ropek8_k<<<2048, blk256, 0, stream>>>(KB, POS);
  attn2_k<<<512, blk256, 0, stream>>>(QB, KB, VTB, KPB, VPTB, CTX, PLEN, POS);

  transpose2_k<<<dim3(64,64,1), blk256, 0, stream>>>(Wo, WOT, HID, HID);
  gemmop_ra_k<<<256, blk512, 0, stream>>>(CTX, WOT, OUT);
}